// Round 1
// baseline (569.564 us; speedup 1.0000x reference)
//
#include <hip/hip_runtime.h>
#include <hip/hip_bf16.h>
#include <math.h>

#define T_LEN 2048
#define RC 256
#define DIM 1024
#define VOCAB 50257

using short8 = __attribute__((ext_vector_type(8))) short;
using f32x4  = __attribute__((ext_vector_type(4))) float;

__device__ __forceinline__ unsigned short f2bf(float f) {
    unsigned int u = __float_as_uint(f);
    u += 0x7fffu + ((u >> 16) & 1u);          // round-to-nearest-even
    return (unsigned short)(u >> 16);
}

__device__ __forceinline__ void async_load16(void* lds, const void* g) {
    __builtin_amdgcn_global_load_lds(
        (const __attribute__((address_space(1))) void*)g,
        (__attribute__((address_space(3))) void*)lds,
        16, 0, 0);
}

// ---------------- K1: MU = gather(token_to_mu_w^T, ids) + pos ----------------
__global__ __launch_bounds__(256) void mu_kernel(
    const int* __restrict__ ids, const float* __restrict__ tokw,
    const float* __restrict__ pos, float* __restrict__ mu) {
    int t = blockIdx.x, k = threadIdx.x;
    int id = ids[t];
    float v = tokw[(size_t)k * VOCAB + id] + pos[t * RC + k];
    mu[t * RC + k] = v;
}

// ---------------- K2: h_pre = gelu(MU @ w1^T + b1) ----------------
// grid (128, 4): block = 16 tokens x 256 output cols. fp32 exact-ish.
__global__ __launch_bounds__(256) void gemm1_gelu_kernel(
    const float* __restrict__ mu, const float* __restrict__ w1,
    const float* __restrict__ b1, float* __restrict__ hpre) {
    __shared__ float xs[16][RC];
    const int tg = blockIdx.x, ng = blockIdx.y, tid = threadIdx.x;
    const int t0 = tg * 16;
    // stage x tile: 16*256 floats
    {
        const float4* src = (const float4*)(mu + (size_t)t0 * RC);
        float4* dst = (float4*)&xs[0][0];
        #pragma unroll
        for (int i = 0; i < 4; ++i) dst[tid + 256 * i] = src[tid + 256 * i];
    }
    __syncthreads();
    const int d = ng * 256 + tid;
    float acc[16];
    const float bias = b1[d];
    #pragma unroll
    for (int t = 0; t < 16; ++t) acc[t] = bias;
    const float4* w1r = (const float4*)(w1 + (size_t)d * RC);
    for (int k4 = 0; k4 < RC / 4; ++k4) {
        const float4 w = w1r[k4];
        #pragma unroll
        for (int t = 0; t < 16; ++t) {
            const float4 xv = *(const float4*)&xs[t][k4 * 4];
            acc[t] += w.x * xv.x + w.y * xv.y + w.z * xv.z + w.w * xv.w;
        }
    }
    #pragma unroll
    for (int t = 0; t < 16; ++t) {
        float x = acc[t];
        float g = 0.5f * x * (1.0f + erff(x * 0.70710678118654752f));
        hpre[(size_t)(t0 + t) * DIM + d] = g;
    }
}

// ---------------- K3: LayerNorm -> bf16 h ----------------
__global__ __launch_bounds__(256) void ln_kernel(
    const float* __restrict__ hpre, const float* __restrict__ lnw,
    const float* __restrict__ lnb, unsigned short* __restrict__ h) {
    const int t = blockIdx.x, tid = threadIdx.x;
    const float4 v = ((const float4*)(hpre + (size_t)t * DIM))[tid];
    float s  = v.x + v.y + v.z + v.w;
    float ss = v.x * v.x + v.y * v.y + v.z * v.z + v.w * v.w;
    #pragma unroll
    for (int off = 32; off > 0; off >>= 1) {
        s  += __shfl_down(s, off, 64);
        ss += __shfl_down(ss, off, 64);
    }
    __shared__ float red[8];
    const int wid = tid >> 6, lane = tid & 63;
    if (lane == 0) { red[wid] = s; red[4 + wid] = ss; }
    __syncthreads();
    const float S  = red[0] + red[1] + red[2] + red[3];
    const float SS = red[4] + red[5] + red[6] + red[7];
    const float mean = S * (1.0f / DIM);
    const float var  = SS * (1.0f / DIM) - mean * mean;
    const float inv  = 1.0f / sqrtf(var + 1e-6f);
    const float4 wv = ((const float4*)lnw)[tid];
    const float4 bv = ((const float4*)lnb)[tid];
    ushort4 o;
    o.x = f2bf((v.x - mean) * inv * wv.x + bv.x);
    o.y = f2bf((v.y - mean) * inv * wv.y + bv.y);
    o.z = f2bf((v.z - mean) * inv * wv.z + bv.z);
    o.w = f2bf((v.w - mean) * inv * wv.w + bv.w);
    ((ushort4*)h)[(size_t)t * (DIM / 4) + tid] = o;
}

// ---------------- K4: w2 f32 -> bf16 ----------------
__global__ __launch_bounds__(256) void cvt_kernel(
    const float* __restrict__ src, unsigned short* __restrict__ dst, int n4) {
    int i = blockIdx.x * 256 + threadIdx.x;
    const int stride = gridDim.x * 256;
    for (; i < n4; i += stride) {
        const float4 v = ((const float4*)src)[i];
        ushort4 o;
        o.x = f2bf(v.x); o.y = f2bf(v.y); o.z = f2bf(v.z); o.w = f2bf(v.w);
        ((ushort4*)dst)[i] = o;
    }
}

// ---------------- K5: logits = h @ w2^T + b2 (bf16 MFMA, m97 structure) ----------------
// A [2048][1024] bf16 row-major (K contig), B [50257][1024] bf16 row-major (K contig).
// 128x128 tile, BK=64, 4 waves 2x2, each wave 64x64 = 4x4 frags of 16x16x32.
__global__ __launch_bounds__(256) void gemm2_kernel(
    const unsigned short* __restrict__ A, const unsigned short* __restrict__ B,
    const float* __restrict__ b2, float* __restrict__ out) {
    __shared__ unsigned short As[128 * 64];
    __shared__ unsigned short Bs[128 * 64];

    const int tid  = threadIdx.x;
    const int bid  = blockIdx.x;
    const int m0   = (bid & 15) << 7;   // 16 M-tiles fastest: 16 consecutive blocks share B panel
    const int n0   = (bid >> 4) << 7;
    const int wid  = tid >> 6;
    const int lane = tid & 63;
    const int wm   = wid >> 1, wn = wid & 1;
    const int lr   = lane & 15;
    const int lk   = lane >> 4;

    const f32x4 zero = {0.f, 0.f, 0.f, 0.f};
    f32x4 acc[4][4];
    #pragma unroll
    for (int m = 0; m < 4; ++m)
        #pragma unroll
        for (int n = 0; n < 4; ++n) acc[m][n] = zero;

    for (int kt = 0; kt < DIM / 64; ++kt) {
        // stage A & B tiles: 128 rows x 64 cols bf16 = 16KB each, 16B granules
        #pragma unroll
        for (int it = 0; it < 4; ++it) {
            const int g   = it * 256 + tid;
            const int row = g >> 3, c8 = g & 7;
            async_load16(As + g * 8,
                         A + (size_t)(m0 + row) * DIM + kt * 64 + c8 * 8);
            int bn = n0 + row; if (bn > VOCAB - 1) bn = VOCAB - 1;
            async_load16(Bs + g * 8,
                         B + (size_t)bn * DIM + kt * 64 + c8 * 8);
        }
        __syncthreads();
        #pragma unroll
        for (int kk = 0; kk < 2; ++kk) {
            short8 af[4], bfr[4];
            #pragma unroll
            for (int m = 0; m < 4; ++m)
                af[m] = *(const short8*)&As[(wm * 64 + m * 16 + lr) * 64 + kk * 32 + lk * 8];
            #pragma unroll
            for (int n = 0; n < 4; ++n)
                bfr[n] = *(const short8*)&Bs[(wn * 64 + n * 16 + lr) * 64 + kk * 32 + lk * 8];
            #pragma unroll
            for (int m = 0; m < 4; ++m)
                #pragma unroll
                for (int n = 0; n < 4; ++n)
                    acc[m][n] = __builtin_amdgcn_mfma_f32_16x16x32_bf16(
                        af[m], bfr[n], acc[m][n], 0, 0, 0);
        }
        __syncthreads();
    }

    // epilogue: C row = (lane>>4)*4 + reg, col = lane&15  [measured m89/m91]
    #pragma unroll
    for (int m = 0; m < 4; ++m) {
        const int row = m0 + wm * 64 + m * 16 + lk * 4;
        #pragma unroll
        for (int n = 0; n < 4; ++n) {
            const int col = n0 + wn * 64 + n * 16 + lr;
            if (col < VOCAB) {
                const float bias = b2[col];
                #pragma unroll
                for (int j = 0; j < 4; ++j)
                    out[(size_t)(row + j) * VOCAB + col] = acc[m][n][j] + bias;
            }
        }
    }
}

extern "C" void kernel_launch(void* const* d_in, const int* in_sizes, int n_in,
                              void* d_out, int out_size, void* d_ws, size_t ws_size,
                              hipStream_t stream) {
    (void)in_sizes; (void)n_in; (void)out_size; (void)ws_size;
    const int*   ids  = (const int*)d_in[0];
    const float* tokw = (const float*)d_in[1];
    const float* pos  = (const float*)d_in[2];
    const float* w1   = (const float*)d_in[3];
    const float* b1   = (const float*)d_in[4];
    const float* lnw  = (const float*)d_in[5];
    const float* lnb  = (const float*)d_in[6];
    const float* w2   = (const float*)d_in[7];
    const float* b2   = (const float*)d_in[8];

    float* logits = (float*)d_out;
    float* mu_out = logits + (size_t)T_LEN * VOCAB;            // MU output region

    // workspace: [w2 bf16 102.9MB][h bf16 4MB]
    unsigned short* w2b = (unsigned short*)d_ws;
    unsigned short* hb  = (unsigned short*)((char*)d_ws + (size_t)VOCAB * DIM * 2);
    float* hpre = logits;   // scratch in logits region; overwritten by K5 later

    mu_kernel<<<dim3(T_LEN), dim3(256), 0, stream>>>(ids, tokw, pos, mu_out);
    gemm1_gelu_kernel<<<dim3(T_LEN / 16, DIM / 256), dim3(256), 0, stream>>>(
        mu_out, w1, b1, hpre);
    ln_kernel<<<dim3(T_LEN), dim3(256), 0, stream>>>(hpre, lnw, lnb, hb);
    cvt_kernel<<<dim3(2048), dim3(256), 0, stream>>>(
        w2, w2b, (int)((size_t)VOCAB * DIM / 4));
    const int ntiles_n = (VOCAB + 127) / 128;   // 393
    gemm2_kernel<<<dim3(16 * ntiles_n), dim3(256), 0, stream>>>(hb, w2b, b2, logits);
}

// Round 2
// 491.567 us; speedup vs baseline: 1.1587x; 1.1587x over previous
//
#include <hip/hip_runtime.h>
#include <hip/hip_bf16.h>
#include <math.h>

#define T_LEN 2048
#define RC 256
#define DIM 1024
#define VOCAB 50257
#define NT 32              // K tiles: 1024 / 32
#define SLOT 8192          // ushorts per LDS tile slot: 256 rows x 32 cols

using short8 = __attribute__((ext_vector_type(8))) short;
using f32x4  = __attribute__((ext_vector_type(4))) float;

#define VMCNT(n) asm volatile("s_waitcnt vmcnt(" #n ")" ::: "memory")
#define SCHED_FENCE() __builtin_amdgcn_sched_barrier(0)

__device__ __forceinline__ unsigned short f2bf(float f) {
    unsigned int u = __float_as_uint(f);
    u += 0x7fffu + ((u >> 16) & 1u);          // round-to-nearest-even
    return (unsigned short)(u >> 16);
}

__device__ __forceinline__ void async_load16(void* lds, const void* g) {
    __builtin_amdgcn_global_load_lds(
        (const __attribute__((address_space(1))) void*)g,
        (__attribute__((address_space(3))) void*)lds,
        16, 0, 0);
}

// ---------------- K1: MU = gather(token_to_mu_w^T, ids) + pos ----------------
__global__ __launch_bounds__(256) void mu_kernel(
    const int* __restrict__ ids, const float* __restrict__ tokw,
    const float* __restrict__ pos, float* __restrict__ mu) {
    int t = blockIdx.x, k = threadIdx.x;
    int id = ids[t];
    float v = tokw[(size_t)k * VOCAB + id] + pos[t * RC + k];
    mu[t * RC + k] = v;
}

// ---------------- K2: h_pre = gelu(MU @ w1^T + b1) ----------------
__global__ __launch_bounds__(256) void gemm1_gelu_kernel(
    const float* __restrict__ mu, const float* __restrict__ w1,
    const float* __restrict__ b1, float* __restrict__ hpre) {
    __shared__ float xs[16][RC];
    const int tg = blockIdx.x, ng = blockIdx.y, tid = threadIdx.x;
    const int t0 = tg * 16;
    {
        const float4* src = (const float4*)(mu + (size_t)t0 * RC);
        float4* dst = (float4*)&xs[0][0];
        #pragma unroll
        for (int i = 0; i < 4; ++i) dst[tid + 256 * i] = src[tid + 256 * i];
    }
    __syncthreads();
    const int d = ng * 256 + tid;
    float acc[16];
    const float bias = b1[d];
    #pragma unroll
    for (int t = 0; t < 16; ++t) acc[t] = bias;
    const float4* w1r = (const float4*)(w1 + (size_t)d * RC);
    for (int k4 = 0; k4 < RC / 4; ++k4) {
        const float4 w = w1r[k4];
        #pragma unroll
        for (int t = 0; t < 16; ++t) {
            const float4 xv = *(const float4*)&xs[t][k4 * 4];
            acc[t] += w.x * xv.x + w.y * xv.y + w.z * xv.z + w.w * xv.w;
        }
    }
    #pragma unroll
    for (int t = 0; t < 16; ++t) {
        float x = acc[t];
        float g = 0.5f * x * (1.0f + erff(x * 0.70710678118654752f));
        hpre[(size_t)(t0 + t) * DIM + d] = g;
    }
}

// ---------------- K3: LayerNorm -> bf16 h ----------------
__global__ __launch_bounds__(256) void ln_kernel(
    const float* __restrict__ hpre, const float* __restrict__ lnw,
    const float* __restrict__ lnb, unsigned short* __restrict__ h) {
    const int t = blockIdx.x, tid = threadIdx.x;
    const float4 v = ((const float4*)(hpre + (size_t)t * DIM))[tid];
    float s  = v.x + v.y + v.z + v.w;
    float ss = v.x * v.x + v.y * v.y + v.z * v.z + v.w * v.w;
    #pragma unroll
    for (int off = 32; off > 0; off >>= 1) {
        s  += __shfl_down(s, off, 64);
        ss += __shfl_down(ss, off, 64);
    }
    __shared__ float red[8];
    const int wid = tid >> 6, lane = tid & 63;
    if (lane == 0) { red[wid] = s; red[4 + wid] = ss; }
    __syncthreads();
    const float S  = red[0] + red[1] + red[2] + red[3];
    const float SS = red[4] + red[5] + red[6] + red[7];
    const float mean = S * (1.0f / DIM);
    const float var  = SS * (1.0f / DIM) - mean * mean;
    const float inv  = 1.0f / sqrtf(var + 1e-6f);
    const float4 wv = ((const float4*)lnw)[tid];
    const float4 bv = ((const float4*)lnb)[tid];
    ushort4 o;
    o.x = f2bf((v.x - mean) * inv * wv.x + bv.x);
    o.y = f2bf((v.y - mean) * inv * wv.y + bv.y);
    o.z = f2bf((v.z - mean) * inv * wv.z + bv.z);
    o.w = f2bf((v.w - mean) * inv * wv.w + bv.w);
    ((ushort4*)h)[(size_t)t * (DIM / 4) + tid] = o;
}

// ---------------- K4: w2 f32 -> bf16 ----------------
__global__ __launch_bounds__(256) void cvt_kernel(
    const float* __restrict__ src, unsigned short* __restrict__ dst, int n4) {
    int i = blockIdx.x * 256 + threadIdx.x;
    const int stride = gridDim.x * 256;
    for (; i < n4; i += stride) {
        const float4 v = ((const float4*)src)[i];
        ushort4 o;
        o.x = f2bf(v.x); o.y = f2bf(v.y); o.z = f2bf(v.z); o.w = f2bf(v.w);
        ((ushort4*)dst)[i] = o;
    }
}

// ---------------- K5: logits = h @ w2^T + b2 ----------------
// 256x256 tile, BK=32, ring of 4 LDS tile-slots (prefetch distance 3),
// 8 waves (2M x 4N), phase-interleaved with counted vmcnt (T3+T4),
// XOR-swizzled LDS (T2), setprio around MFMA (T5), XCD swizzle (T1).
__device__ __forceinline__ void stage_tile_part(
    const unsigned short* __restrict__ A, const unsigned short* __restrict__ B,
    unsigned short* As_s, unsigned short* Bs_s,
    int m0, int n0, int kt, int it, int tid, int lk_src) {
    const int row = it * 128 + (tid >> 2);
    // linear LDS dest granule p = it*512 + tid holds global granule lk_src
    async_load16(As_s + (size_t)(it * 512 + tid) * 8,
                 A + (size_t)(m0 + row) * DIM + kt * 32 + lk_src * 8);
    int bn = n0 + row; if (bn > VOCAB - 1) bn = VOCAB - 1;
    async_load16(Bs_s + (size_t)(it * 512 + tid) * 8,
                 B + (size_t)bn * DIM + kt * 32 + lk_src * 8);
}

__global__ __launch_bounds__(512, 2) void gemm2_kernel(
    const unsigned short* __restrict__ A, const unsigned short* __restrict__ B,
    const float* __restrict__ b2, float* __restrict__ out) {
    __shared__ unsigned short As[4 * SLOT];   // 64 KiB
    __shared__ unsigned short Bs[4 * SLOT];   // 64 KiB

    const int tid  = threadIdx.x;
    // T1: bijective XCD swizzle (gridDim.x % 8 == 0), M-fastest within chunk
    const int cpx  = gridDim.x >> 3;
    const int wgid = (blockIdx.x & 7) * cpx + (blockIdx.x >> 3);
    const int m0   = (wgid & 7) << 8;
    const int n0   = (wgid >> 3) << 8;

    const int lane = tid & 63;
    const int lr   = lane & 15;
    const int lk   = lane >> 4;
    const int wid  = tid >> 6;
    const int wr   = wid >> 2;          // 0..1
    const int wc   = wid & 3;           // 0..3
    // T2 read-side swizzle: slot = lk ^ ((row>>1)&3); row bits that matter = lr
    const int xr      = (lk ^ ((lr >> 1) & 3)) * 8;    // ushort offset in row
    const int arow0   = wr * 128 + lr;
    const int brow0   = wc * 64 + lr;
    // T2 source-side swizzle for linear global_load_lds dest
    const int lk_src  = (tid & 3) ^ ((tid >> 3) & 3);

    f32x4 acc[8][4];
    #pragma unroll
    for (int m = 0; m < 8; ++m)
        #pragma unroll
        for (int n = 0; n < 4; ++n) acc[m][n] = {0.f, 0.f, 0.f, 0.f};

    // prologue: stage tiles 0,1,2 (order fenced so vmcnt accounting is exact)
    #pragma unroll
    for (int tt = 0; tt < 3; ++tt) {
        stage_tile_part(A, B, As + tt * SLOT, Bs + tt * SLOT, m0, n0, tt, 0, tid, lk_src);
        stage_tile_part(A, B, As + tt * SLOT, Bs + tt * SLOT, m0, n0, tt, 1, tid, lk_src);
        SCHED_FENCE();
    }
    VMCNT(8);                       // retire tile 0 (oldest 4 of 12)
    __builtin_amdgcn_s_barrier();

    #pragma unroll 1
    for (int t = 0; t < NT; ++t) {
        const unsigned short* As_t = As + (t & 3) * SLOT;
        const unsigned short* Bs_t = Bs + (t & 3) * SLOT;
        unsigned short* As_s = As + ((t + 3) & 3) * SLOT;
        unsigned short* Bs_s = Bs + ((t + 3) & 3) * SLOT;
        const bool do_stage = (t + 3 < NT);
        short8 af[4], bf[4];

        // ---- phase 1: C-quadrant m0-3 x n0-3 ----
        #pragma unroll
        for (int n = 0; n < 4; ++n)
            bf[n] = *(const short8*)(Bs_t + (brow0 + n * 16) * 32 + xr);
        #pragma unroll
        for (int m = 0; m < 4; ++m)
            af[m] = *(const short8*)(As_t + (arow0 + m * 16) * 32 + xr);
        if (do_stage)
            stage_tile_part(A, B, As_s, Bs_s, m0, n0, t + 3, 0, tid, lk_src);
        SCHED_FENCE();
        __builtin_amdgcn_s_barrier();
        __builtin_amdgcn_s_setprio(1);
        #pragma unroll
        for (int m = 0; m < 4; ++m)
            #pragma unroll
            for (int n = 0; n < 4; ++n)
                acc[m][n] = __builtin_amdgcn_mfma_f32_16x16x32_bf16(
                    af[m], bf[n], acc[m][n], 0, 0, 0);
        __builtin_amdgcn_s_setprio(0);
        SCHED_FENCE();
        __builtin_amdgcn_s_barrier();

        // ---- phase 2: C-quadrant m4-7 x n0-3 (reuse bf) ----
        #pragma unroll
        for (int m = 0; m < 4; ++m)
            af[m] = *(const short8*)(As_t + (arow0 + (m + 4) * 16) * 32 + xr);
        if (do_stage)
            stage_tile_part(A, B, As_s, Bs_s, m0, n0, t + 3, 1, tid, lk_src);
        SCHED_FENCE();
        // counted vmcnt: retire tile t+1 before next iteration reads it
        if (t < NT - 3)       { VMCNT(8); }
        else if (t == NT - 3) { VMCNT(4); }
        else                  { VMCNT(0); }
        __builtin_amdgcn_s_barrier();
        __builtin_amdgcn_s_setprio(1);
        #pragma unroll
        for (int m = 0; m < 4; ++m)
            #pragma unroll
            for (int n = 0; n < 4; ++n)
                acc[m + 4][n] = __builtin_amdgcn_mfma_f32_16x16x32_bf16(
                    af[m], bf[n], acc[m + 4][n], 0, 0, 0);
        __builtin_amdgcn_s_setprio(0);
        SCHED_FENCE();
        __builtin_amdgcn_s_barrier();
    }

    // epilogue: C row = frag_row + (lane>>4)*4 + j, col = lane&15
    #pragma unroll
    for (int m = 0; m < 8; ++m) {
        const int row = m0 + wr * 128 + m * 16 + lk * 4;
        #pragma unroll
        for (int n = 0; n < 4; ++n) {
            const int col = n0 + wc * 64 + n * 16 + lr;
            if (col < VOCAB) {
                const float bias = b2[col];
                #pragma unroll
                for (int j = 0; j < 4; ++j)
                    out[(size_t)(row + j) * VOCAB + col] = acc[m][n][j] + bias;
            }
        }
    }
}

extern "C" void kernel_launch(void* const* d_in, const int* in_sizes, int n_in,
                              void* d_out, int out_size, void* d_ws, size_t ws_size,
                              hipStream_t stream) {
    (void)in_sizes; (void)n_in; (void)out_size; (void)ws_size;
    const int*   ids  = (const int*)d_in[0];
    const float* tokw = (const float*)d_in[1];
    const float* pos  = (const float*)d_in[2];
    const float* w1   = (const float*)d_in[3];
    const float* b1   = (const float*)d_in[4];
    const float* lnw  = (const float*)d_in[5];
    const float* lnb  = (const float*)d_in[6];
    const float* w2   = (const float*)d_in[7];
    const float* b2   = (const float*)d_in[8];

    float* logits = (float*)d_out;
    float* mu_out = logits + (size_t)T_LEN * VOCAB;            // MU output region

    unsigned short* w2b = (unsigned short*)d_ws;
    unsigned short* hb  = (unsigned short*)((char*)d_ws + (size_t)VOCAB * DIM * 2);
    float* hpre = logits;   // scratch in logits region; overwritten by K5 later

    mu_kernel<<<dim3(T_LEN), dim3(256), 0, stream>>>(ids, tokw, pos, mu_out);
    gemm1_gelu_kernel<<<dim3(T_LEN / 16, DIM / 256), dim3(256), 0, stream>>>(
        mu_out, w1, b1, hpre);
    ln_kernel<<<dim3(T_LEN), dim3(256), 0, stream>>>(hpre, lnw, lnb, hb);
    cvt_kernel<<<dim3(2048), dim3(256), 0, stream>>>(
        w2, w2b, (int)((size_t)VOCAB * DIM / 4));
    const int ntiles_n = (VOCAB + 255) / 256;   // 197
    gemm2_kernel<<<dim3(8 * ntiles_n), dim3(512), 0, stream>>>(hb, w2b, b2, logits);
}

// Round 3
// 476.635 us; speedup vs baseline: 1.1950x; 1.0313x over previous
//
#include <hip/hip_runtime.h>
#include <hip/hip_bf16.h>
#include <math.h>

#define T_LEN 2048
#define RC 256
#define DIM 1024
#define VOCAB 50257
#define NT 32              // K tiles: 1024 / 32
#define SLOT 4096          // ushorts per LDS tile slot: 128 rows x 32 cols

using short8 = __attribute__((ext_vector_type(8))) short;
using f32x4  = __attribute__((ext_vector_type(4))) float;

#define VMCNT(n) asm volatile("s_waitcnt vmcnt(" #n ")" ::: "memory")
#define SCHED_FENCE() __builtin_amdgcn_sched_barrier(0)

__device__ __forceinline__ unsigned short f2bf(float f) {
    unsigned int u = __float_as_uint(f);
    u += 0x7fffu + ((u >> 16) & 1u);          // round-to-nearest-even
    return (unsigned short)(u >> 16);
}

__device__ __forceinline__ void async_load16(void* lds, const void* g) {
    __builtin_amdgcn_global_load_lds(
        (const __attribute__((address_space(1))) void*)g,
        (__attribute__((address_space(3))) void*)lds,
        16, 0, 0);
}

// ---------------- K1: MU = gather(token_to_mu_w^T, ids) + pos ----------------
__global__ __launch_bounds__(256) void mu_kernel(
    const int* __restrict__ ids, const float* __restrict__ tokw,
    const float* __restrict__ pos, float* __restrict__ mu) {
    int t = blockIdx.x, k = threadIdx.x;
    int id = ids[t];
    float v = tokw[(size_t)k * VOCAB + id] + pos[t * RC + k];
    mu[t * RC + k] = v;
}

// ---------------- K2: h_pre = gelu(MU @ w1^T + b1) ----------------
__global__ __launch_bounds__(256) void gemm1_gelu_kernel(
    const float* __restrict__ mu, const float* __restrict__ w1,
    const float* __restrict__ b1, float* __restrict__ hpre) {
    __shared__ float xs[16][RC];
    const int tg = blockIdx.x, ng = blockIdx.y, tid = threadIdx.x;
    const int t0 = tg * 16;
    {
        const float4* src = (const float4*)(mu + (size_t)t0 * RC);
        float4* dst = (float4*)&xs[0][0];
        #pragma unroll
        for (int i = 0; i < 4; ++i) dst[tid + 256 * i] = src[tid + 256 * i];
    }
    __syncthreads();
    const int d = ng * 256 + tid;
    float acc[16];
    const float bias = b1[d];
    #pragma unroll
    for (int t = 0; t < 16; ++t) acc[t] = bias;
    const float4* w1r = (const float4*)(w1 + (size_t)d * RC);
    for (int k4 = 0; k4 < RC / 4; ++k4) {
        const float4 w = w1r[k4];
        #pragma unroll
        for (int t = 0; t < 16; ++t) {
            const float4 xv = *(const float4*)&xs[t][k4 * 4];
            acc[t] += w.x * xv.x + w.y * xv.y + w.z * xv.z + w.w * xv.w;
        }
    }
    #pragma unroll
    for (int t = 0; t < 16; ++t) {
        float x = acc[t];
        float g = 0.5f * x * (1.0f + erff(x * 0.70710678118654752f));
        hpre[(size_t)(t0 + t) * DIM + d] = g;
    }
}

// ---------------- K3: LayerNorm -> bf16 h ----------------
__global__ __launch_bounds__(256) void ln_kernel(
    const float* __restrict__ hpre, const float* __restrict__ lnw,
    const float* __restrict__ lnb, unsigned short* __restrict__ h) {
    const int t = blockIdx.x, tid = threadIdx.x;
    const float4 v = ((const float4*)(hpre + (size_t)t * DIM))[tid];
    float s  = v.x + v.y + v.z + v.w;
    float ss = v.x * v.x + v.y * v.y + v.z * v.z + v.w * v.w;
    #pragma unroll
    for (int off = 32; off > 0; off >>= 1) {
        s  += __shfl_down(s, off, 64);
        ss += __shfl_down(ss, off, 64);
    }
    __shared__ float red[8];
    const int wid = tid >> 6, lane = tid & 63;
    if (lane == 0) { red[wid] = s; red[4 + wid] = ss; }
    __syncthreads();
    const float S  = red[0] + red[1] + red[2] + red[3];
    const float SS = red[4] + red[5] + red[6] + red[7];
    const float mean = S * (1.0f / DIM);
    const float var  = SS * (1.0f / DIM) - mean * mean;
    const float inv  = 1.0f / sqrtf(var + 1e-6f);
    const float4 wv = ((const float4*)lnw)[tid];
    const float4 bv = ((const float4*)lnb)[tid];
    ushort4 o;
    o.x = f2bf((v.x - mean) * inv * wv.x + bv.x);
    o.y = f2bf((v.y - mean) * inv * wv.y + bv.y);
    o.z = f2bf((v.z - mean) * inv * wv.z + bv.z);
    o.w = f2bf((v.w - mean) * inv * wv.w + bv.w);
    ((ushort4*)h)[(size_t)t * (DIM / 4) + tid] = o;
}

// ---------------- K4: w2 f32 -> bf16 ----------------
__global__ __launch_bounds__(256) void cvt_kernel(
    const float* __restrict__ src, unsigned short* __restrict__ dst, int n4) {
    int i = blockIdx.x * 256 + threadIdx.x;
    const int stride = gridDim.x * 256;
    for (; i < n4; i += stride) {
        const float4 v = ((const float4*)src)[i];
        ushort4 o;
        o.x = f2bf(v.x); o.y = f2bf(v.y); o.z = f2bf(v.z); o.w = f2bf(v.w);
        ((ushort4*)dst)[i] = o;
    }
}

// ---------------- K5: logits = h @ w2^T + b2 ----------------
// 128x128 block, BK=32, ring-3 LDS (stage distance 2, counted vmcnt(4)),
// 4 waves (2x2, wave tile 64x64), T1 XCD swizzle, T2 XOR swizzle, T5 setprio.
// 3 blocks/CU so epilogue/prologue of one block overlaps others' MFMA.
__device__ __forceinline__ void stage_tile(
    const unsigned short* __restrict__ A, const unsigned short* __restrict__ B,
    unsigned short* As_s, unsigned short* Bs_s,
    int m0, int n0, int kt, int tid, int lk_src) {
    #pragma unroll
    for (int p = 0; p < 2; ++p) {
        const int g = p * 256 + tid;
        const int row = g >> 2;
        async_load16(As_s + (size_t)g * 8,
                     A + (size_t)(m0 + row) * DIM + kt * 32 + lk_src * 8);
    }
    #pragma unroll
    for (int p = 0; p < 2; ++p) {
        const int g = p * 256 + tid;
        const int row = g >> 2;
        int bn = n0 + row; if (bn > VOCAB - 1) bn = VOCAB - 1;
        async_load16(Bs_s + (size_t)g * 8,
                     B + (size_t)bn * DIM + kt * 32 + lk_src * 8);
    }
}

__global__ __launch_bounds__(256, 3) void gemm2_kernel(
    const unsigned short* __restrict__ A, const unsigned short* __restrict__ B,
    const float* __restrict__ b2, float* __restrict__ out) {
    __shared__ unsigned short As[3 * SLOT];   // 24 KiB
    __shared__ unsigned short Bs[3 * SLOT];   // 24 KiB

    const int tid  = threadIdx.x;
    // T1: bijective XCD swizzle (gridDim.x = 6288, % 8 == 0), M-fastest
    const int cpx  = gridDim.x >> 3;
    const int wgid = (blockIdx.x & 7) * cpx + (blockIdx.x >> 3);
    const int m0   = (wgid & 15) << 7;
    const int n0   = (wgid >> 4) << 7;

    const int lane = tid & 63;
    const int lr   = lane & 15;
    const int lk   = lane >> 4;
    const int wid  = tid >> 6;
    const int wr   = wid >> 1;          // 0..1
    const int wc   = wid & 1;           // 0..1
    // T2 read-side swizzle (verified conflict-free in R2): granule = lk ^ ((row>>1)&3)
    const int xr     = (lk ^ ((lr >> 1) & 3)) * 8;     // ushort offset within row
    const int arow0  = wr * 64 + lr;
    const int brow0  = wc * 64 + lr;
    // T2 source-side swizzle (inverse, same involution)
    const int lk_src = (tid & 3) ^ ((tid >> 3) & 3);

    f32x4 acc[4][4];
    #pragma unroll
    for (int m = 0; m < 4; ++m)
        #pragma unroll
        for (int n = 0; n < 4; ++n) acc[m][n] = {0.f, 0.f, 0.f, 0.f};

    // prologue: stage tiles 0,1 (ordered so vmcnt counting is exact)
    stage_tile(A, B, As, Bs, m0, n0, 0, tid, lk_src);
    SCHED_FENCE();
    stage_tile(A, B, As + SLOT, Bs + SLOT, m0, n0, 1, tid, lk_src);
    SCHED_FENCE();
    VMCNT(4);                       // retire tile 0 (oldest 4 of 8)
    __builtin_amdgcn_s_barrier();

    int cur = 0, st2 = 2;           // read slot, stage slot for t+2
    #pragma unroll 1
    for (int t = 0; t < NT; ++t) {
        const unsigned short* As_t = As + cur * SLOT;
        const unsigned short* Bs_t = Bs + cur * SLOT;
        short8 af[4], bf[4];
        #pragma unroll
        for (int m = 0; m < 4; ++m)
            af[m] = *(const short8*)(As_t + (arow0 + m * 16) * 32 + xr);
        #pragma unroll
        for (int n = 0; n < 4; ++n)
            bf[n] = *(const short8*)(Bs_t + (brow0 + n * 16) * 32 + xr);
        if (t + 2 < NT)
            stage_tile(A, B, As + st2 * SLOT, Bs + st2 * SLOT, m0, n0, t + 2, tid, lk_src);
        SCHED_FENCE();
        // counted vmcnt: retire tile t+1 (needed next iter); keep t+2 in flight
        if (t < NT - 2) { VMCNT(4); } else { VMCNT(0); }
        __builtin_amdgcn_s_barrier();
        __builtin_amdgcn_s_setprio(1);
        #pragma unroll
        for (int m = 0; m < 4; ++m)
            #pragma unroll
            for (int n = 0; n < 4; ++n)
                acc[m][n] = __builtin_amdgcn_mfma_f32_16x16x32_bf16(
                    af[m], bf[n], acc[m][n], 0, 0, 0);
        __builtin_amdgcn_s_setprio(0);
        SCHED_FENCE();
        __builtin_amdgcn_s_barrier();
        if (++cur == 3) cur = 0;
        if (++st2 == 3) st2 = 0;
    }

    // epilogue: C row = frag_row + (lane>>4)*4 + j, col = lane&15
    float bias[4]; int col[4]; bool ok[4];
    #pragma unroll
    for (int n = 0; n < 4; ++n) {
        col[n] = n0 + wc * 64 + n * 16 + lr;
        ok[n]  = col[n] < VOCAB;
        bias[n] = ok[n] ? b2[col[n]] : 0.f;
    }
    #pragma unroll
    for (int m = 0; m < 4; ++m) {
        const int row = m0 + wr * 64 + m * 16 + lk * 4;
        #pragma unroll
        for (int n = 0; n < 4; ++n) {
            if (ok[n]) {
                #pragma unroll
                for (int j = 0; j < 4; ++j)
                    out[(size_t)(row + j) * VOCAB + col[n]] = acc[m][n][j] + bias[n];
            }
        }
    }
}

extern "C" void kernel_launch(void* const* d_in, const int* in_sizes, int n_in,
                              void* d_out, int out_size, void* d_ws, size_t ws_size,
                              hipStream_t stream) {
    (void)in_sizes; (void)n_in; (void)out_size; (void)ws_size;
    const int*   ids  = (const int*)d_in[0];
    const float* tokw = (const float*)d_in[1];
    const float* pos  = (const float*)d_in[2];
    const float* w1   = (const float*)d_in[3];
    const float* b1   = (const float*)d_in[4];
    const float* lnw  = (const float*)d_in[5];
    const float* lnb  = (const float*)d_in[6];
    const float* w2   = (const float*)d_in[7];
    const float* b2   = (const float*)d_in[8];

    float* logits = (float*)d_out;
    float* mu_out = logits + (size_t)T_LEN * VOCAB;            // MU output region

    unsigned short* w2b = (unsigned short*)d_ws;
    unsigned short* hb  = (unsigned short*)((char*)d_ws + (size_t)VOCAB * DIM * 2);
    float* hpre = logits;   // scratch in logits region; overwritten by K5 later

    mu_kernel<<<dim3(T_LEN), dim3(256), 0, stream>>>(ids, tokw, pos, mu_out);
    gemm1_gelu_kernel<<<dim3(T_LEN / 16, DIM / 256), dim3(256), 0, stream>>>(
        mu_out, w1, b1, hpre);
    ln_kernel<<<dim3(T_LEN), dim3(256), 0, stream>>>(hpre, lnw, lnb, hb);
    cvt_kernel<<<dim3(2048), dim3(256), 0, stream>>>(
        w2, w2b, (int)((size_t)VOCAB * DIM / 4));
    const int ntiles_n = (VOCAB + 127) / 128;   // 393
    gemm2_kernel<<<dim3(16 * ntiles_n), dim3(256), 0, stream>>>(hb, w2b, b2, logits);
}